// Round 1
// baseline (131.875 us; speedup 1.0000x reference)
//
#include <hip/hip_runtime.h>
#include <math.h>

#define B_ 4
#define N_ 8
#define C_ 256
#define H_ 64
#define Wd_ 64
#define K_ 4
#define HID_ 256
#define NA_ 5
#define HW_ (H_*Wd_)          // 4096
#define DIN_ (3*C_+K_)        // 772

#define READOUT_N (B_*N_*C_*HW_)            // 33554432
#define W_OFF    READOUT_N                   // [B,N,K]  128
#define Q_OFF    (W_OFF   + B_*N_*K_)        // [B,N,5]  160
#define ACT_OFF  (Q_OFF   + B_*N_*NA_)       // [B,N]    32
#define ENT_OFF  (ACT_OFF + B_*N_)           // [B,N]    32
#define HIST_OFF (ENT_OFF + B_*N_)           // [5]      5

// ---------------- Kernel A: masked mean pool -> z[b,n,c] ----------------
__global__ __launch_bounds__(256) void pool_kernel(const float* __restrict__ value,
                                                   const float* __restrict__ mask,
                                                   float* __restrict__ z) {
    const int bnc = blockIdx.x;          // 0..8191
    const int bn  = bnc >> 8;            // C_=256
    const int tid = threadIdx.x;
    const float4* vp = (const float4*)value + (size_t)bnc * (HW_/4);
    const float4* mp = (const float4*)mask  + (size_t)bn  * (HW_/4);
    float smv = 0.f, sv = 0.f, sm = 0.f;
    #pragma unroll
    for (int i = 0; i < (HW_/4)/256; ++i) {      // 4 iterations
        float4 v = vp[tid + i*256];
        float4 m = mp[tid + i*256];
        smv += v.x*m.x + v.y*m.y + v.z*m.z + v.w*m.w;
        sv  += v.x + v.y + v.z + v.w;
        sm  += m.x + m.y + m.z + m.w;
    }
    #pragma unroll
    for (int o = 32; o > 0; o >>= 1) {
        smv += __shfl_down(smv, o);
        sv  += __shfl_down(sv, o);
        sm  += __shfl_down(sm, o);
    }
    __shared__ float red[3][4];
    const int lane = tid & 63, wid = tid >> 6;
    if (lane == 0) { red[0][wid] = smv; red[1][wid] = sv; red[2][wid] = sm; }
    __syncthreads();
    if (tid == 0) {
        float t_smv = red[0][0]+red[0][1]+red[0][2]+red[0][3];
        float t_sv  = red[1][0]+red[1][1]+red[1][2]+red[1][3];
        float t_sm  = red[2][0]+red[2][1]+red[2][2]+red[2][3];
        float pooled = t_smv / fmaxf(t_sm, 1e-6f);
        float fb     = t_sv * (1.0f/HW_);
        z[bnc] = (t_sm > 1e-5f) ? pooled : fb;
    }
}

// ---------------- Kernel B: retrieval + spawn + MLP head ----------------
__global__ __launch_bounds__(256) void brain_kernel(
    const float* __restrict__ z,    const float* __restrict__ keys,
    const float* __restrict__ vel,  const int*   __restrict__ valid,
    const float* __restrict__ W1,   const float* __restrict__ b1,
    const float* __restrict__ W2,   const float* __restrict__ b2,
    float* __restrict__ delta_ws,   float* __restrict__ out)
{
    const int bn = blockIdx.x, tid = threadIdx.x;
    __shared__ float z_s[C_];
    __shared__ float key2[K_][C_];
    __shared__ float vel2[K_][C_];
    __shared__ float qs[DIN_];
    __shared__ float h_s[HID_];
    __shared__ float red[K_][4];
    __shared__ float w_s[K_];
    __shared__ float q_s[NA_];
    __shared__ int   wr_s[K_];
    __shared__ int   valid2_s[K_];

    z_s[tid] = z[bn*C_ + tid];
    if (tid == 0) {
        int v[K_]; bool anyv = false;
        for (int k = 0; k < K_; ++k) { v[k] = (valid[bn*K_ + k] != 0); anyv = anyv || v[k]; }
        int slot = 0;                                 // argmax(~valid): first invalid, 0 if all valid
        for (int k = K_-1; k >= 0; --k) if (!v[k]) slot = k;
        const bool need = !anyv;
        for (int k = 0; k < K_; ++k) {
            int wr = (need && k == slot) ? 1 : 0;
            wr_s[k] = wr;
            valid2_s[k] = v[k] | wr;
        }
    }
    __syncthreads();
    #pragma unroll
    for (int k = 0; k < K_; ++k) {
        key2[k][tid] = wr_s[k] ? z_s[tid] : keys[((size_t)bn*K_+k)*C_ + tid];
        vel2[k][tid] = wr_s[k] ? 0.f      : vel [((size_t)bn*K_+k)*C_ + tid];
    }
    __syncthreads();
    float part[K_];
    #pragma unroll
    for (int k = 0; k < K_; ++k) { float d = z_s[tid] - key2[k][tid]; part[k] = d*d; }
    #pragma unroll
    for (int o = 32; o > 0; o >>= 1) {
        #pragma unroll
        for (int k = 0; k < K_; ++k) part[k] += __shfl_down(part[k], o);
    }
    const int lane = tid & 63, wid = tid >> 6;
    if (lane == 0) { for (int k = 0; k < K_; ++k) red[k][wid] = part[k]; }
    __syncthreads();
    if (tid == 0) {
        float logit[K_], m = -3e38f;
        bool has = false;
        for (int k = 0; k < K_; ++k) {
            float dist = red[k][0]+red[k][1]+red[k][2]+red[k][3];
            bool vk = valid2_s[k] != 0;
            has = has || vk;
            logit[k] = vk ? -dist : -1e30f;          // TEMP = 1
            m = fmaxf(m, logit[k]);
        }
        float s = 0.f, e[K_];
        for (int k = 0; k < K_; ++k) { e[k] = expf(logit[k] - m); s += e[k]; }
        for (int k = 0; k < K_; ++k) w_s[k] = has ? e[k]/s : 0.f;
    }
    __syncthreads();
    float vb = 0.f;
    #pragma unroll
    for (int k = 0; k < K_; ++k) vb += w_s[k] * vel2[k][tid];    // DT = 1
    const float zc = z_s[tid];
    delta_ws[bn*C_ + tid] = vb;                                   // z_next - z
    qs[tid]        = zc;
    qs[C_   + tid] = zc + vb;
    qs[2*C_ + tid] = vb;
    if (tid < K_) qs[3*C_ + tid] = w_s[tid];
    __syncthreads();
    float acc = b1[tid];
    for (int i = 0; i < DIN_; ++i) acc = fmaf(qs[i], W1[(size_t)i*HID_ + tid], acc);
    h_s[tid] = fmaxf(acc, 0.f);
    __syncthreads();
    if (tid < NA_) {
        float a = b2[tid];
        for (int j = 0; j < HID_; ++j) a = fmaf(h_s[j], W2[(size_t)j*NA_ + tid], a);
        q_s[tid] = a;
    }
    __syncthreads();
    if (tid == 0) {
        bool full = true;
        for (int k = 0; k < K_; ++k) full = full && (valid2_s[k] != 0);
        float best = -3.0e38f; int act = 0;
        for (int a = 0; a < NA_; ++a) {
            bool am = (a < NA_-1) || (!full);
            float qv = am ? q_s[a] : -1e9f;
            out[Q_OFF + bn*NA_ + a] = qv;
            if (qv > best) { best = qv; act = a; }   // strict > keeps first max
        }
        float ent = 0.f;
        for (int k = 0; k < K_; ++k) {
            out[W_OFF + bn*K_ + k] = w_s[k];
            float wc = fmaxf(w_s[k], 1e-8f);
            ent -= wc * logf(wc);
        }
        out[ACT_OFF + bn] = (float)act;
        out[ENT_OFF + bn] = ent;
    }
}

// ---------------- Kernel C: readout = value + gate*delta, + hist ----------------
__global__ __launch_bounds__(256) void readout_kernel(const float* __restrict__ value,
                                                      const float* __restrict__ delta,
                                                      const float* __restrict__ gate,
                                                      float* __restrict__ out) {
    if (blockIdx.x == 0 && threadIdx.x < NA_) {
        // actions were written by brain_kernel (stream-ordered); fold hist here.
        float cnt = 0.f;
        for (int i = 0; i < B_*N_; ++i)
            if ((int)out[ACT_OFF + i] == (int)threadIdx.x) cnt += 1.f;
        out[HIST_OFF + threadIdx.x] = cnt * (1.0f/(B_*N_));
    }
    const float g = gate[0];
    const float4* vp = (const float4*)value;
    float4* op = (float4*)out;
    const int n4 = READOUT_N/4;                      // 8388608
    for (int i = blockIdx.x*blockDim.x + threadIdx.x; i < n4; i += gridDim.x*blockDim.x) {
        float4 v = vp[i];
        float gd = g * delta[i >> 10];               // 1024 float4 per (b,n,c) plane
        v.x += gd; v.y += gd; v.z += gd; v.w += gd;
        op[i] = v;
    }
}

extern "C" void kernel_launch(void* const* d_in, const int* in_sizes, int n_in,
                              void* d_out, int out_size, void* d_ws, size_t ws_size,
                              hipStream_t stream) {
    const float* value = (const float*)d_in[0];
    const float* mask  = (const float*)d_in[1];
    const float* keys  = (const float*)d_in[2];
    const float* vel   = (const float*)d_in[3];
    const int*   valid = (const int*)  d_in[4];
    const float* W1    = (const float*)d_in[5];
    const float* b1    = (const float*)d_in[6];
    const float* W2    = (const float*)d_in[7];
    const float* b2    = (const float*)d_in[8];
    const float* gate  = (const float*)d_in[9];
    float* out = (float*)d_out;

    float* z_ws     = (float*)d_ws;            // B*N*C floats
    float* delta_ws = z_ws + B_*N_*C_;         // B*N*C floats

    pool_kernel<<<B_*N_*C_, 256, 0, stream>>>(value, mask, z_ws);
    brain_kernel<<<B_*N_, 256, 0, stream>>>(z_ws, keys, vel, valid, W1, b1, W2, b2, delta_ws, out);
    readout_kernel<<<2048, 256, 0, stream>>>(value, delta_ws, gate, out);
}

// Round 2
// 84.710 us; speedup vs baseline: 1.5568x; 1.5568x over previous
//
#include <hip/hip_runtime.h>
#include <math.h>

#define B_ 4
#define N_ 8
#define C_ 256
#define H_ 64
#define Wd_ 64
#define K_ 4
#define HID_ 256
#define NA_ 5
#define HW_ (H_*Wd_)          // 4096
#define DIN_ (3*C_+K_)        // 772
#define QS_STRIDE 800

#define READOUT_N (B_*N_*C_*HW_)            // 33554432
#define W_OFF    READOUT_N                   // [B,N,K]  128
#define Q_OFF    (W_OFF   + B_*N_*K_)        // [B,N,5]  160
#define ACT_OFF  (Q_OFF   + B_*N_*NA_)       // [B,N]    32
#define ENT_OFF  (ACT_OFF + B_*N_)           // [B,N]    32
#define HIST_OFF (ENT_OFF + B_*N_)           // [5]      5

// ---------------- Kernel A: masked mean pool -> z[b,n,c] ----------------
__global__ __launch_bounds__(256) void pool_kernel(const float* __restrict__ value,
                                                   const float* __restrict__ mask,
                                                   float* __restrict__ z) {
    const int bnc = blockIdx.x;          // 0..8191
    const int bn  = bnc >> 8;            // C_=256
    const int tid = threadIdx.x;
    const float4* vp = (const float4*)value + (size_t)bnc * (HW_/4);
    const float4* mp = (const float4*)mask  + (size_t)bn  * (HW_/4);
    float smv = 0.f, sv = 0.f, sm = 0.f;
    #pragma unroll
    for (int i = 0; i < (HW_/4)/256; ++i) {      // 4 iterations
        float4 v = vp[tid + i*256];
        float4 m = mp[tid + i*256];
        smv += v.x*m.x + v.y*m.y + v.z*m.z + v.w*m.w;
        sv  += v.x + v.y + v.z + v.w;
        sm  += m.x + m.y + m.z + m.w;
    }
    #pragma unroll
    for (int o = 32; o > 0; o >>= 1) {
        smv += __shfl_down(smv, o);
        sv  += __shfl_down(sv, o);
        sm  += __shfl_down(sm, o);
    }
    __shared__ float red[3][4];
    const int lane = tid & 63, wid = tid >> 6;
    if (lane == 0) { red[0][wid] = smv; red[1][wid] = sv; red[2][wid] = sm; }
    __syncthreads();
    if (tid == 0) {
        float t_smv = red[0][0]+red[0][1]+red[0][2]+red[0][3];
        float t_sv  = red[1][0]+red[1][1]+red[1][2]+red[1][3];
        float t_sm  = red[2][0]+red[2][1]+red[2][2]+red[2][3];
        float pooled = t_smv / fmaxf(t_sm, 1e-6f);
        float fb     = t_sv * (1.0f/HW_);
        z[bnc] = (t_sm > 1e-5f) ? pooled : fb;
    }
}

// ---------------- Kernel B1: retrieval + spawn -> qs, delta, w, entropy ----------------
__global__ __launch_bounds__(256) void retrieve_kernel(
    const float* __restrict__ z,    const float* __restrict__ keys,
    const float* __restrict__ vel,  const int*   __restrict__ valid,
    float* __restrict__ qs_ws,      float* __restrict__ delta_ws,
    float* __restrict__ full_ws,    float* __restrict__ out)
{
    const int bn = blockIdx.x, tid = threadIdx.x;
    __shared__ float z_s[C_];
    __shared__ float key2[K_][C_];
    __shared__ float vel2[K_][C_];
    __shared__ float red[K_][4];
    __shared__ float w_s[K_];
    __shared__ int   wr_s[K_];
    __shared__ int   valid2_s[K_];

    z_s[tid] = z[bn*C_ + tid];
    if (tid == 0) {
        int v[K_]; bool anyv = false;
        for (int k = 0; k < K_; ++k) { v[k] = (valid[bn*K_ + k] != 0); anyv = anyv || v[k]; }
        int slot = 0;                                 // argmax(~valid): first invalid, 0 if all valid
        for (int k = K_-1; k >= 0; --k) if (!v[k]) slot = k;
        const bool need = !anyv;
        for (int k = 0; k < K_; ++k) {
            int wr = (need && k == slot) ? 1 : 0;
            wr_s[k] = wr;
            valid2_s[k] = v[k] | wr;
        }
    }
    __syncthreads();
    #pragma unroll
    for (int k = 0; k < K_; ++k) {
        key2[k][tid] = wr_s[k] ? z_s[tid] : keys[((size_t)bn*K_+k)*C_ + tid];
        vel2[k][tid] = wr_s[k] ? 0.f      : vel [((size_t)bn*K_+k)*C_ + tid];
    }
    __syncthreads();
    float part[K_];
    #pragma unroll
    for (int k = 0; k < K_; ++k) { float d = z_s[tid] - key2[k][tid]; part[k] = d*d; }
    #pragma unroll
    for (int o = 32; o > 0; o >>= 1) {
        #pragma unroll
        for (int k = 0; k < K_; ++k) part[k] += __shfl_down(part[k], o);
    }
    const int lane = tid & 63, wid = tid >> 6;
    if (lane == 0) { for (int k = 0; k < K_; ++k) red[k][wid] = part[k]; }
    __syncthreads();
    if (tid == 0) {
        float logit[K_], m = -3e38f;
        bool has = false;
        for (int k = 0; k < K_; ++k) {
            float dist = red[k][0]+red[k][1]+red[k][2]+red[k][3];
            bool vk = valid2_s[k] != 0;
            has = has || vk;
            logit[k] = vk ? -dist : -1e30f;          // TEMP = 1
            m = fmaxf(m, logit[k]);
        }
        float s = 0.f, e[K_];
        for (int k = 0; k < K_; ++k) { e[k] = expf(logit[k] - m); s += e[k]; }
        for (int k = 0; k < K_; ++k) w_s[k] = has ? e[k]/s : 0.f;
        bool full = true;
        for (int k = 0; k < K_; ++k) full = full && (valid2_s[k] != 0);
        full_ws[bn] = full ? 1.f : 0.f;
        float ent = 0.f;
        for (int k = 0; k < K_; ++k) {
            out[W_OFF + bn*K_ + k] = w_s[k];
            float wc = fmaxf(w_s[k], 1e-8f);
            ent -= wc * logf(wc);
        }
        out[ENT_OFF + bn] = ent;
    }
    __syncthreads();
    float vb = 0.f;
    #pragma unroll
    for (int k = 0; k < K_; ++k) vb += w_s[k] * vel2[k][tid];    // DT = 1
    const float zc = z_s[tid];
    delta_ws[bn*C_ + tid] = vb;                                   // z_next - z
    float* qrow = qs_ws + bn*QS_STRIDE;
    qrow[tid]        = zc;
    qrow[C_   + tid] = zc + vb;
    qrow[2*C_ + tid] = vb;
    if (tid < K_) qrow[3*C_ + tid] = w_s[tid];
}

// ---------------- Kernel B2: MLP layer 1 (h = relu(qs @ W1 + b1)) ----------------
// grid = 32 bn * 8 jchunks; block = 256 = 32 j * 8 igroups
__global__ __launch_bounds__(256) void mlp1_kernel(const float* __restrict__ qs_ws,
                                                   const float* __restrict__ W1,
                                                   const float* __restrict__ b1,
                                                   float* __restrict__ h_ws) {
    const int blk = blockIdx.x;
    const int bn = blk >> 3, jb = blk & 7;
    const int tid = threadIdx.x;
    const int jg = tid & 31, ig = tid >> 5;     // 8 i-groups
    const int j = jb*32 + jg;
    __shared__ float qs[DIN_];
    for (int i = tid; i < DIN_; i += 256) qs[i] = qs_ws[bn*QS_STRIDE + i];
    __syncthreads();
    float acc = 0.f;
    int i = ig;
    #pragma unroll 8
    for (int t = 0; t < 96; ++t, i += 8)        // covers i in [0,768)
        acc = fmaf(qs[i], W1[(size_t)i*HID_ + j], acc);
    if (ig < 4)                                  // tail i = 768..771
        acc = fmaf(qs[768+ig], W1[(size_t)(768+ig)*HID_ + j], acc);
    __shared__ float part[8][33];
    part[ig][jg] = acc;
    __syncthreads();
    if (tid < 32) {
        float s = 0.f;
        #pragma unroll
        for (int g = 0; g < 8; ++g) s += part[g][tid];
        h_ws[bn*HID_ + jb*32 + tid] = fmaxf(s + b1[jb*32 + tid], 0.f);
    }
}

// ---------------- Kernel C: readout + (block 0) MLP2/argmax/entropy/hist ----------------
__global__ __launch_bounds__(256) void readout_kernel(const float* __restrict__ value,
                                                      const float* __restrict__ delta,
                                                      const float* __restrict__ gate,
                                                      const float* __restrict__ h_ws,
                                                      const float* __restrict__ W2,
                                                      const float* __restrict__ b2,
                                                      const float* __restrict__ full_ws,
                                                      float* __restrict__ out) {
    if (blockIdx.x == 0) {
        const int tid = threadIdx.x;
        __shared__ float qq[B_*N_][NA_];
        __shared__ int   act_s[B_*N_];
        if (tid < B_*N_*NA_) {                   // 160 threads: one (bn, action) each
            const int bn = tid / NA_, a = tid % NA_;
            float acc = b2[a];
            const float* hp = h_ws + bn*HID_;
            #pragma unroll 8
            for (int jj = 0; jj < HID_; ++jj)
                acc = fmaf(hp[jj], W2[jj*NA_ + a], acc);
            const bool masked = (a == NA_-1) && (full_ws[bn] != 0.f);
            float qv = masked ? -1e9f : acc;
            out[Q_OFF + bn*NA_ + a] = qv;
            qq[bn][a] = qv;
        }
        __syncthreads();
        if (tid < B_*N_) {
            float best = -3.0e38f; int act = 0;
            #pragma unroll
            for (int a = 0; a < NA_; ++a) {
                float qv = qq[tid][a];
                if (qv > best) { best = qv; act = a; }   // strict > keeps first max
            }
            out[ACT_OFF + tid] = (float)act;
            act_s[tid] = act;
        }
        __syncthreads();
        if (tid < NA_) {
            float cnt = 0.f;
            for (int i = 0; i < B_*N_; ++i)
                if (act_s[i] == (int)tid) cnt += 1.f;
            out[HIST_OFF + tid] = cnt * (1.0f/(B_*N_));
        }
    }
    const float g = gate[0];
    const float4* vp = (const float4*)value;
    float4* op = (float4*)out;
    const int n4 = READOUT_N/4;                  // 8388608
    for (int i = blockIdx.x*blockDim.x + threadIdx.x; i < n4; i += gridDim.x*blockDim.x) {
        float4 v = vp[i];
        float gd = g * delta[i >> 10];           // 1024 float4 per (b,n,c) plane
        v.x += gd; v.y += gd; v.z += gd; v.w += gd;
        op[i] = v;
    }
}

extern "C" void kernel_launch(void* const* d_in, const int* in_sizes, int n_in,
                              void* d_out, int out_size, void* d_ws, size_t ws_size,
                              hipStream_t stream) {
    const float* value = (const float*)d_in[0];
    const float* mask  = (const float*)d_in[1];
    const float* keys  = (const float*)d_in[2];
    const float* vel   = (const float*)d_in[3];
    const int*   valid = (const int*)  d_in[4];
    const float* W1    = (const float*)d_in[5];
    const float* b1    = (const float*)d_in[6];
    const float* W2    = (const float*)d_in[7];
    const float* b2    = (const float*)d_in[8];
    const float* gate  = (const float*)d_in[9];
    float* out = (float*)d_out;

    float* z_ws     = (float*)d_ws;                  // 8192
    float* delta_ws = z_ws     + B_*N_*C_;           // 8192
    float* qs_ws    = delta_ws + B_*N_*C_;           // 32*800 = 25600
    float* h_ws     = qs_ws    + B_*N_*QS_STRIDE;    // 8192
    float* full_ws  = h_ws     + B_*N_*HID_;         // 32

    pool_kernel<<<B_*N_*C_, 256, 0, stream>>>(value, mask, z_ws);
    retrieve_kernel<<<B_*N_, 256, 0, stream>>>(z_ws, keys, vel, valid, qs_ws, delta_ws, full_ws, out);
    mlp1_kernel<<<B_*N_*8, 256, 0, stream>>>(qs_ws, W1, b1, h_ws);
    readout_kernel<<<2048, 256, 0, stream>>>(value, delta_ws, gate, h_ws, W2, b2, full_ws, out);
}

// Round 4
// 72.674 us; speedup vs baseline: 1.8146x; 1.1656x over previous
//
#include <hip/hip_runtime.h>
#include <math.h>

#define B_ 4
#define N_ 8
#define C_ 256
#define H_ 64
#define Wd_ 64
#define K_ 4
#define HID_ 256
#define NA_ 5
#define HW_ (H_*Wd_)          // 4096
#define DIN_ (3*C_+K_)        // 772

typedef float vfloat4 __attribute__((ext_vector_type(4)));

#define READOUT_N (B_*N_*C_*HW_)            // 33554432
#define W_OFF    READOUT_N                   // [B,N,K]  128
#define Q_OFF    (W_OFF   + B_*N_*K_)        // [B,N,5]  160
#define ACT_OFF  (Q_OFF   + B_*N_*NA_)       // [B,N]    32
#define ENT_OFF  (ACT_OFF + B_*N_)           // [B,N]    32
#define HIST_OFF (ENT_OFF + B_*N_)           // [5]      5

// ---------------- Kernel A: masked mean pool -> z[b,n,c] ----------------
__global__ __launch_bounds__(256) void pool_kernel(const float* __restrict__ value,
                                                   const float* __restrict__ mask,
                                                   float* __restrict__ z) {
    const int bnc = blockIdx.x;          // 0..8191
    const int bn  = bnc >> 8;            // C_=256
    const int tid = threadIdx.x;
    const float4* vp = (const float4*)value + (size_t)bnc * (HW_/4);
    const float4* mp = (const float4*)mask  + (size_t)bn  * (HW_/4);
    float smv = 0.f, sv = 0.f, sm = 0.f;
    #pragma unroll
    for (int i = 0; i < (HW_/4)/256; ++i) {      // 4 iterations
        float4 v = vp[tid + i*256];
        float4 m = mp[tid + i*256];
        smv += v.x*m.x + v.y*m.y + v.z*m.z + v.w*m.w;
        sv  += v.x + v.y + v.z + v.w;
        sm  += m.x + m.y + m.z + m.w;
    }
    #pragma unroll
    for (int o = 32; o > 0; o >>= 1) {
        smv += __shfl_down(smv, o);
        sv  += __shfl_down(sv, o);
        sm  += __shfl_down(sm, o);
    }
    __shared__ float red[3][4];
    const int lane = tid & 63, wid = tid >> 6;
    if (lane == 0) { red[0][wid] = smv; red[1][wid] = sv; red[2][wid] = sm; }
    __syncthreads();
    if (tid == 0) {
        float t_smv = red[0][0]+red[0][1]+red[0][2]+red[0][3];
        float t_sv  = red[1][0]+red[1][1]+red[1][2]+red[1][3];
        float t_sm  = red[2][0]+red[2][1]+red[2][2]+red[2][3];
        float pooled = t_smv / fmaxf(t_sm, 1e-6f);
        float fb     = t_sv * (1.0f/HW_);
        z[bnc] = (t_sm > 1e-5f) ? pooled : fb;
    }
}

// ---------------- Kernel B: fused retrieval + spawn + MLP1 ----------------
// grid = 32 bn * 8 jchunks = 256 blocks; retrieval is redundantly recomputed
// per j-chunk block (cheap, L2-hit) to avoid a separate kernel + round trip.
__global__ __launch_bounds__(256) void brain_kernel(
    const float* __restrict__ z,    const float* __restrict__ keys,
    const float* __restrict__ vel,  const int*   __restrict__ valid,
    const float* __restrict__ W1,   const float* __restrict__ b1,
    float* __restrict__ delta_ws,   float* __restrict__ h_ws,
    float* __restrict__ full_ws,    float* __restrict__ out)
{
    const int blk = blockIdx.x;
    const int bn = blk >> 3, jb = blk & 7;
    const int tid = threadIdx.x;
    __shared__ float qs[DIN_];
    __shared__ float red[K_][4];
    __shared__ float w_s[K_];
    __shared__ int   wr_s[K_];
    __shared__ int   valid2_s[K_];

    const float zc = z[bn*C_ + tid];
    if (tid == 0) {
        int v[K_]; bool anyv = false;
        for (int k = 0; k < K_; ++k) { v[k] = (valid[bn*K_ + k] != 0); anyv = anyv || v[k]; }
        int slot = 0;                                 // argmax(~valid): first invalid, 0 if all valid
        for (int k = K_-1; k >= 0; --k) if (!v[k]) slot = k;
        const bool need = !anyv;
        for (int k = 0; k < K_; ++k) {
            int wr = (need && k == slot) ? 1 : 0;
            wr_s[k] = wr;
            valid2_s[k] = v[k] | wr;
        }
    }
    __syncthreads();
    float vv[K_], part[K_];
    #pragma unroll
    for (int k = 0; k < K_; ++k) {
        const float kv = wr_s[k] ? zc : keys[((size_t)bn*K_+k)*C_ + tid];
        vv[k] = wr_s[k] ? 0.f : vel[((size_t)bn*K_+k)*C_ + tid];
        const float d = zc - kv;
        part[k] = d*d;
    }
    #pragma unroll
    for (int o = 32; o > 0; o >>= 1) {
        #pragma unroll
        for (int k = 0; k < K_; ++k) part[k] += __shfl_down(part[k], o);
    }
    const int lane = tid & 63, wid = tid >> 6;
    if (lane == 0) { for (int k = 0; k < K_; ++k) red[k][wid] = part[k]; }
    __syncthreads();
    if (tid == 0) {
        float logit[K_], m = -3e38f;
        bool has = false;
        for (int k = 0; k < K_; ++k) {
            float dist = red[k][0]+red[k][1]+red[k][2]+red[k][3];
            bool vk = valid2_s[k] != 0;
            has = has || vk;
            logit[k] = vk ? -dist : -1e30f;          // TEMP = 1
            m = fmaxf(m, logit[k]);
        }
        float s = 0.f, e[K_];
        for (int k = 0; k < K_; ++k) { e[k] = expf(logit[k] - m); s += e[k]; }
        for (int k = 0; k < K_; ++k) w_s[k] = has ? e[k]/s : 0.f;
        if (jb == 0) {
            bool full = true;
            for (int k = 0; k < K_; ++k) full = full && (valid2_s[k] != 0);
            full_ws[bn] = full ? 1.f : 0.f;
            float ent = 0.f;
            for (int k = 0; k < K_; ++k) {
                out[W_OFF + bn*K_ + k] = w_s[k];
                float wc = fmaxf(w_s[k], 1e-8f);
                ent -= wc * logf(wc);
            }
            out[ENT_OFF + bn] = ent;
        }
    }
    __syncthreads();
    float vb = 0.f;
    #pragma unroll
    for (int k = 0; k < K_; ++k) vb += w_s[k] * vv[k];            // DT = 1
    qs[tid]        = zc;
    qs[C_   + tid] = zc + vb;
    qs[2*C_ + tid] = vb;
    if (tid < K_) qs[3*C_ + tid] = w_s[tid];
    if (jb == 0) delta_ws[bn*C_ + tid] = vb;                      // z_next - z
    __syncthreads();
    // MLP1 chunk: 32 j * 8 i-groups
    const int jg = tid & 31, ig = tid >> 5;
    const int j = jb*32 + jg;
    float acc = 0.f;
    int i = ig;
    #pragma unroll 8
    for (int t = 0; t < 96; ++t, i += 8)        // i in [0,768)
        acc = fmaf(qs[i], W1[(size_t)i*HID_ + j], acc);
    if (ig < 4)                                  // tail i = 768..771
        acc = fmaf(qs[768+ig], W1[(size_t)(768+ig)*HID_ + j], acc);
    __shared__ float part_s[8][33];
    part_s[ig][jg] = acc;
    __syncthreads();
    if (tid < 32) {
        float s = 0.f;
        #pragma unroll
        for (int g = 0; g < 8; ++g) s += part_s[g][tid];
        h_ws[bn*HID_ + jb*32 + tid] = fmaxf(s + b1[jb*32 + tid], 0.f);
    }
}

// ---------------- Kernel C: readout (1 block per plane) + block0 head ----------------
__global__ __launch_bounds__(256) void readout_kernel(const float* __restrict__ value,
                                                      const float* __restrict__ delta,
                                                      const float* __restrict__ gate,
                                                      const float* __restrict__ h_ws,
                                                      const float* __restrict__ W2,
                                                      const float* __restrict__ b2,
                                                      const float* __restrict__ full_ws,
                                                      float* __restrict__ out) {
    const int bnc = blockIdx.x;                  // 0..8191 plane id
    const int tid = threadIdx.x;
    if (bnc == 0) {
        __shared__ float qq[B_*N_][NA_];
        __shared__ int   act_s[B_*N_];
        if (tid < B_*N_*NA_) {                   // 160 threads: one (bn, action) each
            const int bn = tid / NA_, a = tid % NA_;
            float acc = b2[a];
            const float* hp = h_ws + bn*HID_;
            #pragma unroll 8
            for (int jj = 0; jj < HID_; ++jj)
                acc = fmaf(hp[jj], W2[jj*NA_ + a], acc);
            const bool masked = (a == NA_-1) && (full_ws[bn] != 0.f);
            float qv = masked ? -1e9f : acc;
            out[Q_OFF + bn*NA_ + a] = qv;
            qq[bn][a] = qv;
        }
        __syncthreads();
        if (tid < B_*N_) {
            float best = -3.0e38f; int act = 0;
            #pragma unroll
            for (int a = 0; a < NA_; ++a) {
                float qv = qq[tid][a];
                if (qv > best) { best = qv; act = a; }   // strict > keeps first max
            }
            out[ACT_OFF + tid] = (float)act;
            act_s[tid] = act;
        }
        __syncthreads();
        if (tid < NA_) {
            float cnt = 0.f;
            for (int i = 0; i < B_*N_; ++i)
                if (act_s[i] == (int)tid) cnt += 1.f;
            out[HIST_OFF + tid] = cnt * (1.0f/(B_*N_));
        }
    }
    const float gd = gate[0] * delta[bnc];       // uniform per block
    const vfloat4* vp = (const vfloat4*)value + (size_t)bnc * (HW_/4);
    vfloat4*       op = (vfloat4*)out         + (size_t)bnc * (HW_/4);
    #pragma unroll
    for (int t = 0; t < (HW_/4)/256; ++t) {      // 4 iterations
        const int idx = tid + t*256;
        vfloat4 v = __builtin_nontemporal_load(&vp[idx]);
        v += gd;
        __builtin_nontemporal_store(v, &op[idx]);
    }
}

extern "C" void kernel_launch(void* const* d_in, const int* in_sizes, int n_in,
                              void* d_out, int out_size, void* d_ws, size_t ws_size,
                              hipStream_t stream) {
    const float* value = (const float*)d_in[0];
    const float* mask  = (const float*)d_in[1];
    const float* keys  = (const float*)d_in[2];
    const float* vel   = (const float*)d_in[3];
    const int*   valid = (const int*)  d_in[4];
    const float* W1    = (const float*)d_in[5];
    const float* b1    = (const float*)d_in[6];
    const float* W2    = (const float*)d_in[7];
    const float* b2    = (const float*)d_in[8];
    const float* gate  = (const float*)d_in[9];
    float* out = (float*)d_out;

    float* z_ws     = (float*)d_ws;                  // 8192
    float* delta_ws = z_ws     + B_*N_*C_;           // 8192
    float* h_ws     = delta_ws + B_*N_*C_;           // 8192
    float* full_ws  = h_ws     + B_*N_*HID_;         // 32

    pool_kernel<<<B_*N_*C_, 256, 0, stream>>>(value, mask, z_ws);
    brain_kernel<<<B_*N_*8, 256, 0, stream>>>(z_ws, keys, vel, valid, W1, b1, delta_ws, h_ws, full_ws, out);
    readout_kernel<<<B_*N_*C_, 256, 0, stream>>>(value, delta_ws, gate, h_ws, W2, b2, full_ws, out);
}

// Round 5
// 72.485 us; speedup vs baseline: 1.8193x; 1.0026x over previous
//
#include <hip/hip_runtime.h>
#include <math.h>

#define B_ 4
#define N_ 8
#define C_ 256
#define H_ 64
#define Wd_ 64
#define K_ 4
#define HID_ 256
#define NA_ 5
#define HW_ (H_*Wd_)          // 4096
#define DIN_ (3*C_+K_)        // 772

typedef float vfloat4 __attribute__((ext_vector_type(4)));

#define READOUT_N (B_*N_*C_*HW_)            // 33554432
#define W_OFF    READOUT_N                   // [B,N,K]  128
#define Q_OFF    (W_OFF   + B_*N_*K_)        // [B,N,5]  160
#define ACT_OFF  (Q_OFF   + B_*N_*NA_)       // [B,N]    32
#define ENT_OFF  (ACT_OFF + B_*N_)           // [B,N]    32
#define HIST_OFF (ENT_OFF + B_*N_)           // [5]      5

// ---------------- Kernel A: masked mean pool -> z[b,n,c] ----------------
__global__ __launch_bounds__(256) void pool_kernel(const float* __restrict__ value,
                                                   const float* __restrict__ mask,
                                                   float* __restrict__ z) {
    const int bnc = blockIdx.x;          // 0..8191
    const int bn  = bnc >> 8;            // C_=256
    const int tid = threadIdx.x;
    const float4* vp = (const float4*)value + (size_t)bnc * (HW_/4);
    const float4* mp = (const float4*)mask  + (size_t)bn  * (HW_/4);
    float smv = 0.f, sv = 0.f, sm = 0.f;
    #pragma unroll
    for (int i = 0; i < (HW_/4)/256; ++i) {      // 4 iterations
        float4 v = vp[tid + i*256];
        float4 m = mp[tid + i*256];
        smv += v.x*m.x + v.y*m.y + v.z*m.z + v.w*m.w;
        sv  += v.x + v.y + v.z + v.w;
        sm  += m.x + m.y + m.z + m.w;
    }
    #pragma unroll
    for (int o = 32; o > 0; o >>= 1) {
        smv += __shfl_down(smv, o);
        sv  += __shfl_down(sv, o);
        sm  += __shfl_down(sm, o);
    }
    __shared__ float red[3][4];
    const int lane = tid & 63, wid = tid >> 6;
    if (lane == 0) { red[0][wid] = smv; red[1][wid] = sv; red[2][wid] = sm; }
    __syncthreads();
    if (tid == 0) {
        float t_smv = red[0][0]+red[0][1]+red[0][2]+red[0][3];
        float t_sv  = red[1][0]+red[1][1]+red[1][2]+red[1][3];
        float t_sm  = red[2][0]+red[2][1]+red[2][2]+red[2][3];
        float pooled = t_smv / fmaxf(t_sm, 1e-6f);
        float fb     = t_sv * (1.0f/HW_);
        z[bnc] = (t_sm > 1e-5f) ? pooled : fb;
    }
}

// ---------------- Kernel B: fused retrieval + spawn + MLP1 ----------------
// grid = 32 bn * 8 jchunks = 256 blocks; retrieval is redundantly recomputed
// per j-chunk block (cheap, L2-hit) to avoid a separate kernel + round trip.
__global__ __launch_bounds__(256) void brain_kernel(
    const float* __restrict__ z,    const float* __restrict__ keys,
    const float* __restrict__ vel,  const int*   __restrict__ valid,
    const float* __restrict__ W1,   const float* __restrict__ b1,
    float* __restrict__ delta_ws,   float* __restrict__ h_ws,
    float* __restrict__ full_ws,    float* __restrict__ out)
{
    const int blk = blockIdx.x;
    const int bn = blk >> 3, jb = blk & 7;
    const int tid = threadIdx.x;
    __shared__ float qs[DIN_];
    __shared__ float red[K_][4];
    __shared__ float w_s[K_];
    __shared__ int   wr_s[K_];
    __shared__ int   valid2_s[K_];

    const float zc = z[bn*C_ + tid];
    if (tid == 0) {
        int v[K_]; bool anyv = false;
        for (int k = 0; k < K_; ++k) { v[k] = (valid[bn*K_ + k] != 0); anyv = anyv || v[k]; }
        int slot = 0;                                 // argmax(~valid): first invalid, 0 if all valid
        for (int k = K_-1; k >= 0; --k) if (!v[k]) slot = k;
        const bool need = !anyv;
        for (int k = 0; k < K_; ++k) {
            int wr = (need && k == slot) ? 1 : 0;
            wr_s[k] = wr;
            valid2_s[k] = v[k] | wr;
        }
    }
    __syncthreads();
    float vv[K_], part[K_];
    #pragma unroll
    for (int k = 0; k < K_; ++k) {
        const float kv = wr_s[k] ? zc : keys[((size_t)bn*K_+k)*C_ + tid];
        vv[k] = wr_s[k] ? 0.f : vel[((size_t)bn*K_+k)*C_ + tid];
        const float d = zc - kv;
        part[k] = d*d;
    }
    #pragma unroll
    for (int o = 32; o > 0; o >>= 1) {
        #pragma unroll
        for (int k = 0; k < K_; ++k) part[k] += __shfl_down(part[k], o);
    }
    const int lane = tid & 63, wid = tid >> 6;
    if (lane == 0) { for (int k = 0; k < K_; ++k) red[k][wid] = part[k]; }
    __syncthreads();
    if (tid == 0) {
        float logit[K_], m = -3e38f;
        bool has = false;
        for (int k = 0; k < K_; ++k) {
            float dist = red[k][0]+red[k][1]+red[k][2]+red[k][3];
            bool vk = valid2_s[k] != 0;
            has = has || vk;
            logit[k] = vk ? -dist : -1e30f;          // TEMP = 1
            m = fmaxf(m, logit[k]);
        }
        float s = 0.f, e[K_];
        for (int k = 0; k < K_; ++k) { e[k] = expf(logit[k] - m); s += e[k]; }
        for (int k = 0; k < K_; ++k) w_s[k] = has ? e[k]/s : 0.f;
        if (jb == 0) {
            bool full = true;
            for (int k = 0; k < K_; ++k) full = full && (valid2_s[k] != 0);
            full_ws[bn] = full ? 1.f : 0.f;
            float ent = 0.f;
            for (int k = 0; k < K_; ++k) {
                out[W_OFF + bn*K_ + k] = w_s[k];
                float wc = fmaxf(w_s[k], 1e-8f);
                ent -= wc * logf(wc);
            }
            out[ENT_OFF + bn] = ent;
        }
    }
    __syncthreads();
    float vb = 0.f;
    #pragma unroll
    for (int k = 0; k < K_; ++k) vb += w_s[k] * vv[k];            // DT = 1
    qs[tid]        = zc;
    qs[C_   + tid] = zc + vb;
    qs[2*C_ + tid] = vb;
    if (tid < K_) qs[3*C_ + tid] = w_s[tid];
    if (jb == 0) delta_ws[bn*C_ + tid] = vb;                      // z_next - z
    __syncthreads();
    // MLP1 chunk: 32 j * 8 i-groups
    const int jg = tid & 31, ig = tid >> 5;
    const int j = jb*32 + jg;
    float acc = 0.f;
    int i = ig;
    #pragma unroll 8
    for (int t = 0; t < 96; ++t, i += 8)        // i in [0,768)
        acc = fmaf(qs[i], W1[(size_t)i*HID_ + j], acc);
    if (ig < 4)                                  // tail i = 768..771
        acc = fmaf(qs[768+ig], W1[(size_t)(768+ig)*HID_ + j], acc);
    __shared__ float part_s[8][33];
    part_s[ig][jg] = acc;
    __syncthreads();
    if (tid < 32) {
        float s = 0.f;
        #pragma unroll
        for (int g = 0; g < 8; ++g) s += part_s[g][tid];
        h_ws[bn*HID_ + jb*32 + tid] = fmaxf(s + b1[jb*32 + tid], 0.f);
    }
}

// ---------------- Kernel C: readout (1 block per plane) + block0 head ----------------
// value load is a REGULAR cached load (pool just pulled value through L2/L3 —
// an NT load here bypasses that residency and forces HBM fetches).
// out store stays nontemporal so the write stream doesn't evict value.
__global__ __launch_bounds__(256) void readout_kernel(const float* __restrict__ value,
                                                      const float* __restrict__ delta,
                                                      const float* __restrict__ gate,
                                                      const float* __restrict__ h_ws,
                                                      const float* __restrict__ W2,
                                                      const float* __restrict__ b2,
                                                      const float* __restrict__ full_ws,
                                                      float* __restrict__ out) {
    const int bnc = blockIdx.x;                  // 0..8191 plane id
    const int tid = threadIdx.x;
    if (bnc == 0) {
        __shared__ float qq[B_*N_][NA_];
        __shared__ int   act_s[B_*N_];
        if (tid < B_*N_*NA_) {                   // 160 threads: one (bn, action) each
            const int bn = tid / NA_, a = tid % NA_;
            float acc = b2[a];
            const float* hp = h_ws + bn*HID_;
            #pragma unroll 8
            for (int jj = 0; jj < HID_; ++jj)
                acc = fmaf(hp[jj], W2[jj*NA_ + a], acc);
            const bool masked = (a == NA_-1) && (full_ws[bn] != 0.f);
            float qv = masked ? -1e9f : acc;
            out[Q_OFF + bn*NA_ + a] = qv;
            qq[bn][a] = qv;
        }
        __syncthreads();
        if (tid < B_*N_) {
            float best = -3.0e38f; int act = 0;
            #pragma unroll
            for (int a = 0; a < NA_; ++a) {
                float qv = qq[tid][a];
                if (qv > best) { best = qv; act = a; }   // strict > keeps first max
            }
            out[ACT_OFF + tid] = (float)act;
            act_s[tid] = act;
        }
        __syncthreads();
        if (tid < NA_) {
            float cnt = 0.f;
            for (int i = 0; i < B_*N_; ++i)
                if (act_s[i] == (int)tid) cnt += 1.f;
            out[HIST_OFF + tid] = cnt * (1.0f/(B_*N_));
        }
    }
    const float gd = gate[0] * delta[bnc];       // uniform per block
    const vfloat4* vp = (const vfloat4*)value + (size_t)bnc * (HW_/4);
    vfloat4*       op = (vfloat4*)out         + (size_t)bnc * (HW_/4);
    #pragma unroll
    for (int t = 0; t < (HW_/4)/256; ++t) {      // 4 iterations
        const int idx = tid + t*256;
        vfloat4 v = vp[idx];                     // cached load (L3-resident from pool)
        v += gd;
        __builtin_nontemporal_store(v, &op[idx]);
    }
}

extern "C" void kernel_launch(void* const* d_in, const int* in_sizes, int n_in,
                              void* d_out, int out_size, void* d_ws, size_t ws_size,
                              hipStream_t stream) {
    const float* value = (const float*)d_in[0];
    const float* mask  = (const float*)d_in[1];
    const float* keys  = (const float*)d_in[2];
    const float* vel   = (const float*)d_in[3];
    const int*   valid = (const int*)  d_in[4];
    const float* W1    = (const float*)d_in[5];
    const float* b1    = (const float*)d_in[6];
    const float* W2    = (const float*)d_in[7];
    const float* b2    = (const float*)d_in[8];
    const float* gate  = (const float*)d_in[9];
    float* out = (float*)d_out;

    float* z_ws     = (float*)d_ws;                  // 8192
    float* delta_ws = z_ws     + B_*N_*C_;           // 8192
    float* h_ws     = delta_ws + B_*N_*C_;           // 8192
    float* full_ws  = h_ws     + B_*N_*HID_;         // 32

    pool_kernel<<<B_*N_*C_, 256, 0, stream>>>(value, mask, z_ws);
    brain_kernel<<<B_*N_*8, 256, 0, stream>>>(z_ws, keys, vel, valid, W1, b1, delta_ws, h_ws, full_ws, out);
    readout_kernel<<<B_*N_*C_, 256, 0, stream>>>(value, delta_ws, gate, h_ws, W2, b2, full_ws, out);
}

// Round 6
// 72.317 us; speedup vs baseline: 1.8236x; 1.0023x over previous
//
#include <hip/hip_runtime.h>
#include <math.h>

#define B_ 4
#define N_ 8
#define C_ 256
#define H_ 64
#define Wd_ 64
#define K_ 4
#define HID_ 256
#define NA_ 5
#define HW_ (H_*Wd_)          // 4096
#define DIN_ (3*C_+K_)        // 772

typedef float vfloat4 __attribute__((ext_vector_type(4)));

#define READOUT_N (B_*N_*C_*HW_)            // 33554432
#define W_OFF    READOUT_N                   // [B,N,K]  128
#define Q_OFF    (W_OFF   + B_*N_*K_)        // [B,N,5]  160
#define ACT_OFF  (Q_OFF   + B_*N_*NA_)       // [B,N]    32
#define ENT_OFF  (ACT_OFF + B_*N_)           // [B,N]    32
#define HIST_OFF (ENT_OFF + B_*N_)           // [5]      5

// ---------------- Kernel A: masked mean pool -> z[b,n,c] ----------------
__global__ __launch_bounds__(256) void pool_kernel(const float* __restrict__ value,
                                                   const float* __restrict__ mask,
                                                   float* __restrict__ z) {
    const int bnc = blockIdx.x;          // 0..8191
    const int bn  = bnc >> 8;            // C_=256
    const int tid = threadIdx.x;
    const float4* vp = (const float4*)value + (size_t)bnc * (HW_/4);
    const float4* mp = (const float4*)mask  + (size_t)bn  * (HW_/4);
    float smv = 0.f, sv = 0.f, sm = 0.f;
    #pragma unroll
    for (int i = 0; i < (HW_/4)/256; ++i) {      // 4 iterations
        float4 v = vp[tid + i*256];
        float4 m = mp[tid + i*256];
        smv += v.x*m.x + v.y*m.y + v.z*m.z + v.w*m.w;
        sv  += v.x + v.y + v.z + v.w;
        sm  += m.x + m.y + m.z + m.w;
    }
    #pragma unroll
    for (int o = 32; o > 0; o >>= 1) {
        smv += __shfl_down(smv, o);
        sv  += __shfl_down(sv, o);
        sm  += __shfl_down(sm, o);
    }
    __shared__ float red[3][4];
    const int lane = tid & 63, wid = tid >> 6;
    if (lane == 0) { red[0][wid] = smv; red[1][wid] = sv; red[2][wid] = sm; }
    __syncthreads();
    if (tid == 0) {
        float t_smv = red[0][0]+red[0][1]+red[0][2]+red[0][3];
        float t_sv  = red[1][0]+red[1][1]+red[1][2]+red[1][3];
        float t_sm  = red[2][0]+red[2][1]+red[2][2]+red[2][3];
        float pooled = t_smv / fmaxf(t_sm, 1e-6f);
        float fb     = t_sv * (1.0f/HW_);
        z[bnc] = (t_sm > 1e-5f) ? pooled : fb;
    }
}

// ---------------- Kernel B: fused retrieval + spawn + MLP1 ----------------
// grid = 32 bn * 8 jchunks = 256 blocks; retrieval is redundantly recomputed
// per j-chunk block (cheap, L2-hit) to avoid a separate kernel + round trip.
__global__ __launch_bounds__(256) void brain_kernel(
    const float* __restrict__ z,    const float* __restrict__ keys,
    const float* __restrict__ vel,  const int*   __restrict__ valid,
    const float* __restrict__ W1,   const float* __restrict__ b1,
    float* __restrict__ delta_ws,   float* __restrict__ h_ws,
    float* __restrict__ full_ws,    float* __restrict__ out)
{
    const int blk = blockIdx.x;
    const int bn = blk >> 3, jb = blk & 7;
    const int tid = threadIdx.x;
    __shared__ float qs[DIN_];
    __shared__ float red[K_][4];
    __shared__ float w_s[K_];
    __shared__ int   wr_s[K_];
    __shared__ int   valid2_s[K_];

    const float zc = z[bn*C_ + tid];
    if (tid == 0) {
        int v[K_]; bool anyv = false;
        for (int k = 0; k < K_; ++k) { v[k] = (valid[bn*K_ + k] != 0); anyv = anyv || v[k]; }
        int slot = 0;                                 // argmax(~valid): first invalid, 0 if all valid
        for (int k = K_-1; k >= 0; --k) if (!v[k]) slot = k;
        const bool need = !anyv;
        for (int k = 0; k < K_; ++k) {
            int wr = (need && k == slot) ? 1 : 0;
            wr_s[k] = wr;
            valid2_s[k] = v[k] | wr;
        }
    }
    __syncthreads();
    float vv[K_], part[K_];
    #pragma unroll
    for (int k = 0; k < K_; ++k) {
        const float kv = wr_s[k] ? zc : keys[((size_t)bn*K_+k)*C_ + tid];
        vv[k] = wr_s[k] ? 0.f : vel[((size_t)bn*K_+k)*C_ + tid];
        const float d = zc - kv;
        part[k] = d*d;
    }
    #pragma unroll
    for (int o = 32; o > 0; o >>= 1) {
        #pragma unroll
        for (int k = 0; k < K_; ++k) part[k] += __shfl_down(part[k], o);
    }
    const int lane = tid & 63, wid = tid >> 6;
    if (lane == 0) { for (int k = 0; k < K_; ++k) red[k][wid] = part[k]; }
    __syncthreads();
    if (tid == 0) {
        float logit[K_], m = -3e38f;
        bool has = false;
        for (int k = 0; k < K_; ++k) {
            float dist = red[k][0]+red[k][1]+red[k][2]+red[k][3];
            bool vk = valid2_s[k] != 0;
            has = has || vk;
            logit[k] = vk ? -dist : -1e30f;          // TEMP = 1
            m = fmaxf(m, logit[k]);
        }
        float s = 0.f, e[K_];
        for (int k = 0; k < K_; ++k) { e[k] = expf(logit[k] - m); s += e[k]; }
        for (int k = 0; k < K_; ++k) w_s[k] = has ? e[k]/s : 0.f;
        if (jb == 0) {
            bool full = true;
            for (int k = 0; k < K_; ++k) full = full && (valid2_s[k] != 0);
            full_ws[bn] = full ? 1.f : 0.f;
            float ent = 0.f;
            for (int k = 0; k < K_; ++k) {
                out[W_OFF + bn*K_ + k] = w_s[k];
                float wc = fmaxf(w_s[k], 1e-8f);
                ent -= wc * logf(wc);
            }
            out[ENT_OFF + bn] = ent;
        }
    }
    __syncthreads();
    float vb = 0.f;
    #pragma unroll
    for (int k = 0; k < K_; ++k) vb += w_s[k] * vv[k];            // DT = 1
    qs[tid]        = zc;
    qs[C_   + tid] = zc + vb;
    qs[2*C_ + tid] = vb;
    if (tid < K_) qs[3*C_ + tid] = w_s[tid];
    if (jb == 0) delta_ws[bn*C_ + tid] = vb;                      // z_next - z
    __syncthreads();
    // MLP1 chunk: 32 j * 8 i-groups
    const int jg = tid & 31, ig = tid >> 5;
    const int j = jb*32 + jg;
    float acc = 0.f;
    int i = ig;
    #pragma unroll 8
    for (int t = 0; t < 96; ++t, i += 8)        // i in [0,768)
        acc = fmaf(qs[i], W1[(size_t)i*HID_ + j], acc);
    if (ig < 4)                                  // tail i = 768..771
        acc = fmaf(qs[768+ig], W1[(size_t)(768+ig)*HID_ + j], acc);
    __shared__ float part_s[8][33];
    part_s[ig][jg] = acc;
    __syncthreads();
    if (tid < 32) {
        float s = 0.f;
        #pragma unroll
        for (int g = 0; g < 8; ++g) s += part_s[g][tid];
        h_ws[bn*HID_ + jb*32 + tid] = fmaxf(s + b1[jb*32 + tid], 0.f);
    }
}

// ---------------- Kernel C: readout (1 block per plane, REVERSED order) ----------------
// Reverse traversal: pool left L3 with value[0..8191] oldest->newest. Walking
// 8191->0 reads MRU lines first; out-store write-allocations evict the LRU end
// (stale junk, then value[0..] which we read last) instead of chasing the read
// pointer. Same-order traversal measured ~0% L3 hit on the value re-read.
__global__ __launch_bounds__(256) void readout_kernel(const float* __restrict__ value,
                                                      const float* __restrict__ delta,
                                                      const float* __restrict__ gate,
                                                      const float* __restrict__ h_ws,
                                                      const float* __restrict__ W2,
                                                      const float* __restrict__ b2,
                                                      const float* __restrict__ full_ws,
                                                      float* __restrict__ out) {
    const int bnc = (B_*N_*C_ - 1) - blockIdx.x;   // reversed plane id
    const int tid = threadIdx.x;
    if (blockIdx.x == 0) {
        __shared__ float qq[B_*N_][NA_];
        __shared__ int   act_s[B_*N_];
        if (tid < B_*N_*NA_) {                   // 160 threads: one (bn, action) each
            const int bn = tid / NA_, a = tid % NA_;
            float acc = b2[a];
            const float* hp = h_ws + bn*HID_;
            #pragma unroll 8
            for (int jj = 0; jj < HID_; ++jj)
                acc = fmaf(hp[jj], W2[jj*NA_ + a], acc);
            const bool masked = (a == NA_-1) && (full_ws[bn] != 0.f);
            float qv = masked ? -1e9f : acc;
            out[Q_OFF + bn*NA_ + a] = qv;
            qq[bn][a] = qv;
        }
        __syncthreads();
        if (tid < B_*N_) {
            float best = -3.0e38f; int act = 0;
            #pragma unroll
            for (int a = 0; a < NA_; ++a) {
                float qv = qq[tid][a];
                if (qv > best) { best = qv; act = a; }   // strict > keeps first max
            }
            out[ACT_OFF + tid] = (float)act;
            act_s[tid] = act;
        }
        __syncthreads();
        if (tid < NA_) {
            float cnt = 0.f;
            for (int i = 0; i < B_*N_; ++i)
                if (act_s[i] == (int)tid) cnt += 1.f;
            out[HIST_OFF + tid] = cnt * (1.0f/(B_*N_));
        }
    }
    const float gd = gate[0] * delta[bnc];       // uniform per block
    const vfloat4* vp = (const vfloat4*)value + (size_t)bnc * (HW_/4);
    vfloat4*       op = (vfloat4*)out         + (size_t)bnc * (HW_/4);
    #pragma unroll
    for (int t = 0; t < (HW_/4)/256; ++t) {      // 4 iterations
        const int idx = tid + t*256;
        vfloat4 v = vp[idx];                     // cached load (L3 MRU from pool)
        v += gd;
        __builtin_nontemporal_store(v, &op[idx]);
    }
}

extern "C" void kernel_launch(void* const* d_in, const int* in_sizes, int n_in,
                              void* d_out, int out_size, void* d_ws, size_t ws_size,
                              hipStream_t stream) {
    const float* value = (const float*)d_in[0];
    const float* mask  = (const float*)d_in[1];
    const float* keys  = (const float*)d_in[2];
    const float* vel   = (const float*)d_in[3];
    const int*   valid = (const int*)  d_in[4];
    const float* W1    = (const float*)d_in[5];
    const float* b1    = (const float*)d_in[6];
    const float* W2    = (const float*)d_in[7];
    const float* b2    = (const float*)d_in[8];
    const float* gate  = (const float*)d_in[9];
    float* out = (float*)d_out;

    float* z_ws     = (float*)d_ws;                  // 8192
    float* delta_ws = z_ws     + B_*N_*C_;           // 8192
    float* h_ws     = delta_ws + B_*N_*C_;           // 8192
    float* full_ws  = h_ws     + B_*N_*HID_;         // 32

    pool_kernel<<<B_*N_*C_, 256, 0, stream>>>(value, mask, z_ws);
    brain_kernel<<<B_*N_*8, 256, 0, stream>>>(z_ws, keys, vel, valid, W1, b1, delta_ws, h_ws, full_ws, out);
    readout_kernel<<<B_*N_*C_, 256, 0, stream>>>(value, delta_ws, gate, h_ws, W2, b2, full_ws, out);
}